// Round 7
// baseline (400.777 us; speedup 1.0000x reference)
//
#include <hip/hip_runtime.h>
#include <cstdint>

namespace {

constexpr int BPB  = 16;     // batches per block (full rows staged contiguously)
constexpr int NTHR = 256;    // 4 role-waves; lanes 0..15 active in compute
constexpr int RPAD = 571;    // LDS row stride (567+4); odd*... 571%32=27 -> conflict-free lane reads
constexpr int ROWF = 567;    // floats per R_mode batch row (63*9)
constexpr int OUTF = 192;    // floats per output batch row (64*3)
constexpr int DSTR = 101;    // dd scratch row stride (99+2, odd)
constexpr int LDSF = BPB * RPAD + 2 * BPB * 9;   // staging + Mf1/Pf2 = 9424 floats = 37,696 B

__device__ __forceinline__ float sigm_(float x){ return __fdividef(1.f, 1.f+__expf(-x)); }
__device__ __forceinline__ float tanh_(float x){ return __fdividef(2.f, 1.f+__expf(-2.f*x)) - 1.f; }

__global__ __launch_bounds__(NTHR, 2) void gaze_kernel(
    const float* __restrict__ dirg,   // (B,3)
    const float* __restrict__ Rg,     // (B,63,3,3)
    const float* __restrict__ w_ih,   // (12,3)
    const float* __restrict__ w_hh,   // (12,3)
    const float* __restrict__ b_ih,   // (12)
    const float* __restrict__ b_hh,   // (12)
    float* __restrict__ outg)         // (B,64,3)
{
    __shared__ __align__(16) float lds[LDSF];
    float* const mats = lds + BPB * RPAD;   // [2][16][9] Mf1 / Pf2
    float* const dd   = lds;                // aliases staging AFTER bar2: [16][DSTR] dirs[0..32]

    const int tid  = threadIdx.x;
    const int wid  = tid >> 6;
    const int lane = tid & 63;
    const int64_t b0 = (int64_t)blockIdx.x * BPB;

    // ---- phase 1: stage 16 full rows, perfectly linear global reads (one DRAM pass)
    {
        const float4* gsrc = reinterpret_cast<const float4*>(Rg + b0 * (int64_t)ROWF);
        #pragma unroll
        for (int k = 0; k < 9; ++k) {
            const int ft = k * 256 + tid;           // float4 index 0..2267 (16*567/4)
            if (ft < 2268) {
                const float4 v = gsrc[ft];
                const int gf  = ft * 4;
                const int row = gf / ROWF;          // compile-time magic-div
                const int off = gf - row * ROWF;
                if (off <= ROWF - 4) {              // single row: 16-B aligned LDS write
                    *reinterpret_cast<float4*>(&lds[row * RPAD + off]) = v;
                } else {                            // straddles row boundary (12 per block)
                    lds[row * RPAD + off] = v.x;
                    { const int g1=gf+1, r1=g1/ROWF, o1=g1-r1*ROWF; lds[r1*RPAD+o1]=v.y; }
                    { const int g2=gf+2, r2=g2/ROWF, o2=g2-r2*ROWF; lds[r2*RPAD+o2]=v.z; }
                    { const int g3=gf+3, r3=g3/ROWF, o3=g3-r3*ROWF; lds[r3*RPAD+o3]=v.w; }
                }
            }
        }
    }
    __syncthreads();   // bar1: staging complete

    const bool act = (lane < 16);
    const int  bl  = lane & 15;
    const int64_t b = b0 + bl;
    float dx=0.f, dy=0.f, dz=0.f;
    if (act) { dx = dirg[b*3+0]; dy = dirg[b*3+1]; dz = dirg[b*3+2]; }

    float M[9]  = {1.f,0.f,0.f, 0.f,1.f,0.f, 0.f,0.f,1.f};
    float out[48];                       // this role's 48-float output quarter (static idx)
    const float* const myrow = lds + bl * RPAD;

    // ---- phase 2: quarter chains, entirely from LDS (no fences, no global)
    if (act) {
        if (wid == 0) {                  // role0: t=15..0, M<-M@R^T, u(t)=M*dir -> out[3t]
            #pragma unroll
            for (int s = 0; s < 16; ++s) {
                const int t = 15 - s;
                const float* Rl = myrow + t*9;
                const float r0=Rl[0],r1=Rl[1],r2=Rl[2],r3=Rl[3],r4=Rl[4],r5=Rl[5],r6=Rl[6],r7=Rl[7],r8=Rl[8];
                #pragma unroll
                for (int q = 0; q < 3; ++q) {
                    const float a0=M[3*q], a1=M[3*q+1], a2=M[3*q+2];
                    M[3*q]=a0*r0+a1*r1+a2*r2; M[3*q+1]=a0*r3+a1*r4+a2*r5; M[3*q+2]=a0*r6+a1*r7+a2*r8;
                }
                out[3*t]=M[0]*dx+M[1]*dy+M[2]*dz; out[3*t+1]=M[3]*dx+M[4]*dy+M[5]*dz; out[3*t+2]=M[6]*dx+M[7]*dy+M[8]*dz;
            }
        } else if (wid == 1) {           // role1: t=31..16, d[t]=M*dir -> out[3(t-16)]; publish Mf1
            #pragma unroll
            for (int s = 0; s < 16; ++s) {
                const int t = 31 - s;
                const float* Rl = myrow + t*9;
                const float r0=Rl[0],r1=Rl[1],r2=Rl[2],r3=Rl[3],r4=Rl[4],r5=Rl[5],r6=Rl[6],r7=Rl[7],r8=Rl[8];
                #pragma unroll
                for (int q = 0; q < 3; ++q) {
                    const float a0=M[3*q], a1=M[3*q+1], a2=M[3*q+2];
                    M[3*q]=a0*r0+a1*r1+a2*r2; M[3*q+1]=a0*r3+a1*r4+a2*r5; M[3*q+2]=a0*r6+a1*r7+a2*r8;
                }
                const int o = 3*(t-16);
                out[o]=M[0]*dx+M[1]*dy+M[2]*dz; out[o+1]=M[3]*dx+M[4]*dy+M[5]*dz; out[o+2]=M[6]*dx+M[7]*dy+M[8]*dz;
            }
            #pragma unroll
            for (int i = 0; i < 9; ++i) mats[bl*9 + i] = M[i];            // Mf1
        } else if (wid == 2) {           // role2: t=32..46, M<-M@R, out[t+1] -> out[3+3(t-32)]; publish Pf2
            #pragma unroll
            for (int s = 0; s < 15; ++s) {
                const int t = 32 + s;
                const float* Rl = myrow + t*9;
                const float r0=Rl[0],r1=Rl[1],r2=Rl[2],r3=Rl[3],r4=Rl[4],r5=Rl[5],r6=Rl[6],r7=Rl[7],r8=Rl[8];
                #pragma unroll
                for (int q = 0; q < 3; ++q) {
                    const float a0=M[3*q], a1=M[3*q+1], a2=M[3*q+2];
                    M[3*q]=a0*r0+a1*r3+a2*r6; M[3*q+1]=a0*r1+a1*r4+a2*r7; M[3*q+2]=a0*r2+a1*r5+a2*r8;
                }
                const int o = 3 + 3*s;
                out[o]=M[0]*dx+M[1]*dy+M[2]*dz; out[o+1]=M[3]*dx+M[4]*dy+M[5]*dz; out[o+2]=M[6]*dx+M[7]*dy+M[8]*dz;
            }
            #pragma unroll
            for (int i = 0; i < 9; ++i) mats[BPB*9 + bl*9 + i] = M[i];    // Pf2
        } else {                         // role3: t=47..62, q(t)=M*dir -> out[3(t-47)]
            #pragma unroll
            for (int s = 0; s < 16; ++s) {
                const int t = 47 + s;
                const float* Rl = myrow + t*9;
                const float r0=Rl[0],r1=Rl[1],r2=Rl[2],r3=Rl[3],r4=Rl[4],r5=Rl[5],r6=Rl[6],r7=Rl[7],r8=Rl[8];
                #pragma unroll
                for (int q = 0; q < 3; ++q) {
                    const float a0=M[3*q], a1=M[3*q+1], a2=M[3*q+2];
                    M[3*q]=a0*r0+a1*r3+a2*r6; M[3*q+1]=a0*r1+a1*r4+a2*r7; M[3*q+2]=a0*r2+a1*r5+a2*r8;
                }
                const int o = 3*s;
                out[o]=M[0]*dx+M[1]*dy+M[2]*dz; out[o+1]=M[3]*dx+M[4]*dy+M[5]*dz; out[o+2]=M[6]*dx+M[7]*dy+M[8]*dz;
            }
        }
    }
    __syncthreads();   // bar2: mats published; staging dead -> dd may be written

    float* const orow = outg + b * OUTF;
    float wi[12][3], wh[12][3], bs[12];   // role2 wave only (DCE'd elsewhere)

    if (wid == 0) {
        if (act) {   // fixup d[t] = Mf1 @ u(t); deposit to dd; store quarter0 (3 full sectors)
            const float* P = mats + bl*9;
            const float m0=P[0],m1=P[1],m2=P[2],m3=P[3],m4=P[4],m5=P[5],m6=P[6],m7=P[7],m8=P[8];
            #pragma unroll
            for (int t = 0; t < 16; ++t) {
                const float x=out[3*t], y=out[3*t+1], z=out[3*t+2];
                out[3*t]=m0*x+m1*y+m2*z; out[3*t+1]=m3*x+m4*y+m5*z; out[3*t+2]=m6*x+m7*y+m8*z;
            }
            #pragma unroll
            for (int k = 0; k < 48; ++k) dd[bl*DSTR + k] = out[k];
            #pragma unroll
            for (int q = 0; q < 12; ++q)
                *reinterpret_cast<float4*>(orow + 4*q) =
                    make_float4(out[4*q],out[4*q+1],out[4*q+2],out[4*q+3]);
        }
    } else if (wid == 1) {
        if (act) {   // deposit d[16..31]; store quarter1
            #pragma unroll
            for (int k = 0; k < 48; ++k) dd[bl*DSTR + 48 + k] = out[k];
            #pragma unroll
            for (int q = 0; q < 12; ++q)
                *reinterpret_cast<float4*>(orow + 48 + 4*q) =
                    make_float4(out[4*q],out[4*q+1],out[4*q+2],out[4*q+3]);
        }
    } else if (wid == 2) {
        // whole wave: uniform weight loads (scalarizable)
        #pragma unroll
        for (int g = 0; g < 12; ++g) {
            wi[g][0]=w_ih[g*3+0]; wi[g][1]=w_ih[g*3+1]; wi[g][2]=w_ih[g*3+2];
            wh[g][0]=w_hh[g*3+0]; wh[g][1]=w_hh[g*3+1]; wh[g][2]=w_hh[g*3+2];
            bs[g]   = b_ih[g] + b_hh[g];
        }
        if (act) { dd[bl*DSTR+96]=dx; dd[bl*DSTR+97]=dy; dd[bl*DSTR+98]=dz; }
    } else {
        if (act) {   // fixup out[t+1] = Pf2 @ q(t); store quarter3
            const float* P = mats + BPB*9 + bl*9;
            const float m0=P[0],m1=P[1],m2=P[2],m3=P[3],m4=P[4],m5=P[5],m6=P[6],m7=P[7],m8=P[8];
            #pragma unroll
            for (int t = 0; t < 16; ++t) {
                const float x=out[3*t], y=out[3*t+1], z=out[3*t+2];
                out[3*t]=m0*x+m1*y+m2*z; out[3*t+1]=m3*x+m4*y+m5*z; out[3*t+2]=m6*x+m7*y+m8*z;
            }
            #pragma unroll
            for (int q = 0; q < 12; ++q)
                *reinterpret_cast<float4*>(orow + 144 + 4*q) =
                    make_float4(out[4*q],out[4*q+1],out[4*q+2],out[4*q+3]);
        }
    }
    __syncthreads();   // bar3: dd complete

    // ---- phase 4: fused LSTM on role2's wave; h replaces parked slot; store quarter2
    if (wid == 2 && act) {
        const float* x = dd + bl*DSTR;
        float h[3]  = {0.f,0.f,0.f};
        float cc[3] = {0.f,0.f,0.f};
        #pragma unroll
        for (int t = 0; t < 33; ++t) {
            const float x0 = x[3*t], x1 = x[3*t+1], x2 = x[3*t+2];
            float ga[12];
            #pragma unroll
            for (int g = 0; g < 12; ++g)
                ga[g] = bs[g] + wi[g][0]*x0 + wi[g][1]*x1 + wi[g][2]*x2
                              + wh[g][0]*h[0] + wh[g][1]*h[1] + wh[g][2]*h[2];
            float ig[3], fg[3], gg[3], og[3];
            #pragma unroll
            for (int j = 0; j < 3; ++j) {
                ig[j] = sigm_(ga[j]);
                fg[j] = sigm_(ga[3+j]);
                gg[j] = tanh_(ga[6+j]);
                og[j] = sigm_(ga[9+j]);
            }
            #pragma unroll
            for (int j = 0; j < 3; ++j) {
                cc[j] = fg[j]*cc[j] + ig[j]*gg[j];
                h[j]  = og[j]*tanh_(cc[j]);
            }
        }
        out[0]=h[0]; out[1]=h[1]; out[2]=h[2];
        #pragma unroll
        for (int q = 0; q < 12; ++q)
            *reinterpret_cast<float4*>(orow + 96 + 4*q) =
                make_float4(out[4*q],out[4*q+1],out[4*q+2],out[4*q+3]);
    }
}

}  // namespace

extern "C" void kernel_launch(void* const* d_in, const int* in_sizes, int n_in,
                              void* d_out, int out_size, void* d_ws, size_t ws_size,
                              hipStream_t stream) {
    const float* dirg = (const float*)d_in[0];
    const float* Rg   = (const float*)d_in[1];
    // d_in[2] = S_diag: unused by the reference forward
    const float* wih  = (const float*)d_in[3];
    const float* whh  = (const float*)d_in[4];
    const float* bih  = (const float*)d_in[5];
    const float* bhh  = (const float*)d_in[6];
    float* outg = (float*)d_out;

    const int B = in_sizes[0] / 3;      // 65536
    gaze_kernel<<<B / BPB, NTHR, 0, stream>>>(dirg, Rg, wih, whh, bih, bhh, outg);
}